// Round 1
// baseline (694.565 us; speedup 1.0000x reference)
//
#include <hip/hip_runtime.h>
#include <hip/hip_bf16.h>

#define NN 500000
#define TM 64

typedef __bf16 bf16x8 __attribute__((ext_vector_type(8)));
typedef float  fx4    __attribute__((ext_vector_type(4)));

// ---- weight f32 -> bf16 pack: [W1 32768][W2 16384][mW1 32768][mW2 16384] ----
__global__ void cvt_weights(const float* __restrict__ W1, const float* __restrict__ W2,
                            const float* __restrict__ mW1, const float* __restrict__ mW2,
                            __bf16* __restrict__ out) {
    int i = blockIdx.x * 256 + threadIdx.x;
    if (i < 32768)        out[i] = (__bf16)W1[i];
    else if (i < 49152)   out[i] = (__bf16)W2[i - 32768];
    else if (i < 81920)   out[i] = (__bf16)mW1[i - 49152];
    else if (i < 98304)   out[i] = (__bf16)mW2[i - 81920];
}

// per-wave GEMM: A (LDS, swizzled, strideB bytes/row, 64 rows) x B^T (global bf16,
// row-major [128][K]) -> acc[4][2] tiles of 16x16. Wave covers cols [wid*32, wid*32+32).
__device__ __forceinline__ void gemm_block(const __bf16* A, int strideB, int K,
                                           const __bf16* B, int lane, int wid,
                                           fx4 acc[4][2]) {
    const int rl = lane & 15, ks = lane >> 4;
    for (int kt = 0; kt < K; kt += 32) {
        const int kb = 2 * kt + 16 * ks;   // byte offset of this lane's 8-elem k-chunk
        bf16x8 a[4], b[2];
#pragma unroll
        for (int m = 0; m < 4; ++m) {
            int row = m * 16 + rl;
            a[m] = *(const bf16x8*)((const char*)A + row * strideB + (kb ^ ((row & 7) << 4)));
        }
#pragma unroll
        for (int c = 0; c < 2; ++c) {
            int col = wid * 32 + c * 16 + rl;
            b[c] = *(const bf16x8*)((const char*)B + (size_t)col * 2 * K + kb);
        }
#pragma unroll
        for (int m = 0; m < 4; ++m)
#pragma unroll
            for (int c = 0; c < 2; ++c)
                acc[m][c] = __builtin_amdgcn_mfma_f32_16x16x32_bf16(a[m], b[c], acc[m][c], 0, 0, 0);
    }
}

__global__ __launch_bounds__(256) void tgn_layer(
    const float* __restrict__ h_in, const float* __restrict__ feat,
    const float* __restrict__ ts,   const float* __restrict__ lu,
    const float* __restrict__ tw,   const float* __restrict__ tb,
    const float* __restrict__ b1,   const float* __restrict__ b2,
    const float* __restrict__ mb1,  const float* __restrict__ mb2,
    const int* __restrict__ src,    const __bf16* __restrict__ Wp,
    float* __restrict__ h_out) {
    __shared__ __bf16 C[TM * 256];   // 32 KB, swizzled, stride 512 B
    __shared__ __bf16 T[TM * 128];   // 16 KB, swizzled, stride 256 B

    const int tid  = threadIdx.x;
    const int r0   = blockIdx.x * TM;
    const int lane = tid & 63, wid = tid >> 6;
    const int rl   = lane & 15, ks = lane >> 4;

    // ---- Phase 1: C = [ bf16(h_in[src]) | bf16(feat + cos(dt*w+b)) ] ----
    {
        const int rr = tid >> 4;
        const int cc = (tid & 15) * 8;
        const fx4 tw0 = *(const fx4*)(tw + cc), tw1 = *(const fx4*)(tw + cc + 4);
        const fx4 tb0 = *(const fx4*)(tb + cc), tb1 = *(const fx4*)(tb + cc + 4);
        const float i2p = 0.15915494309189535f;
#pragma unroll
        for (int rb = 0; rb < 4; ++rb) {
            int r = rr + rb * 16;
            int i = r0 + r; if (i >= NN) i = NN - 1;
            int s = src[i];
            float dt = ts[i] - lu[s];
            const fx4* hp = (const fx4*)(h_in + (size_t)s * 128 + cc);
            const fx4* fp = (const fx4*)(feat + (size_t)i * 128 + cc);
            fx4 h0 = hp[0], h1 = hp[1], f0 = fp[0], f1 = fp[1];
            bf16x8 hv, fv;
#pragma unroll
            for (int j = 0; j < 4; ++j) {
                hv[j]     = (__bf16)h0[j];
                hv[4 + j] = (__bf16)h1[j];
                float a0 = (dt * tw0[j] + tb0[j]) * i2p;
                float a1 = (dt * tw1[j] + tb1[j]) * i2p;
                fv[j]     = (__bf16)(f0[j] + __builtin_amdgcn_cosf(__builtin_amdgcn_fractf(a0)));
                fv[4 + j] = (__bf16)(f1[j] + __builtin_amdgcn_cosf(__builtin_amdgcn_fractf(a1)));
            }
            int swz = (r & 7) << 4;
            *(bf16x8*)((char*)C + r * 512 + ((2 * cc) ^ swz))       = hv;
            *(bf16x8*)((char*)C + r * 512 + ((256 + 2 * cc) ^ swz)) = fv;
        }
    }
    __syncthreads();

    // ---- Phase 2: t1 = C @ W1^T + b1  -> T (bf16) ----
    {
        fx4 acc[4][2] = {};
        gemm_block(C, 512, 256, Wp, lane, wid, acc);
        float bb0 = b1[wid * 32 + rl], bb1 = b1[wid * 32 + 16 + rl];
#pragma unroll
        for (int m = 0; m < 4; ++m)
#pragma unroll
            for (int c = 0; c < 2; ++c) {
                int col = wid * 32 + c * 16 + rl;
                float bb = c ? bb1 : bb0;
#pragma unroll
                for (int g = 0; g < 4; ++g) {
                    int row = m * 16 + ks * 4 + g;
                    *(__bf16*)((char*)T + row * 256 + ((2 * col) ^ ((row & 7) << 4))) =
                        (__bf16)(acc[m][c][g] + bb);
                }
            }
    }
    __syncthreads();

    // ---- Phase 3: x = [ bf16(h_in[i]) | relu(T @ W2^T + b2) ] into C ----
    {
        const int rr = tid >> 4;
        const int cc = (tid & 15) * 8;
#pragma unroll
        for (int rb = 0; rb < 4; ++rb) {
            int r = rr + rb * 16;
            int i = r0 + r; if (i >= NN) i = NN - 1;
            const fx4* hp = (const fx4*)(h_in + (size_t)i * 128 + cc);
            fx4 h0 = hp[0], h1 = hp[1];
            bf16x8 hv;
#pragma unroll
            for (int j = 0; j < 4; ++j) { hv[j] = (__bf16)h0[j]; hv[4 + j] = (__bf16)h1[j]; }
            *(bf16x8*)((char*)C + r * 512 + ((2 * cc) ^ ((r & 7) << 4))) = hv;
        }
    }
    {
        fx4 acc[4][2] = {};
        gemm_block(T, 256, 128, Wp + 32768, lane, wid, acc);
        float bb0 = b2[wid * 32 + rl], bb1 = b2[wid * 32 + 16 + rl];
#pragma unroll
        for (int m = 0; m < 4; ++m)
#pragma unroll
            for (int c = 0; c < 2; ++c) {
                int col = wid * 32 + c * 16 + rl;
                float bb = c ? bb1 : bb0;
#pragma unroll
                for (int g = 0; g < 4; ++g) {
                    int row = m * 16 + ks * 4 + g;
                    float v = fmaxf(acc[m][c][g] + bb, 0.0f);
                    *(__bf16*)((char*)C + row * 512 + ((256 + 2 * col) ^ ((row & 7) << 4))) = (__bf16)v;
                }
            }
    }
    __syncthreads();

    // ---- Phase 4: m1 = relu(x @ mW1^T + mb1) -> T ----
    {
        fx4 acc[4][2] = {};
        gemm_block(C, 512, 256, Wp + 49152, lane, wid, acc);
        float bb0 = mb1[wid * 32 + rl], bb1 = mb1[wid * 32 + 16 + rl];
#pragma unroll
        for (int m = 0; m < 4; ++m)
#pragma unroll
            for (int c = 0; c < 2; ++c) {
                int col = wid * 32 + c * 16 + rl;
                float bb = c ? bb1 : bb0;
#pragma unroll
                for (int g = 0; g < 4; ++g) {
                    int row = m * 16 + ks * 4 + g;
                    float v = fmaxf(acc[m][c][g] + bb, 0.0f);
                    *(__bf16*)((char*)T + row * 256 + ((2 * col) ^ ((row & 7) << 4))) = (__bf16)v;
                }
            }
    }
    __syncthreads();

    // ---- Phase 5: h_out = m1 @ mW2^T + mb2 ----
    {
        fx4 acc[4][2] = {};
        gemm_block(T, 256, 128, Wp + 81920, lane, wid, acc);
        float bb0 = mb2[wid * 32 + rl], bb1 = mb2[wid * 32 + 16 + rl];
#pragma unroll
        for (int m = 0; m < 4; ++m)
#pragma unroll
            for (int c = 0; c < 2; ++c) {
                int col = wid * 32 + c * 16 + rl;
                float bb = c ? bb1 : bb0;
#pragma unroll
                for (int g = 0; g < 4; ++g) {
                    int row = m * 16 + ks * 4 + g;
                    int i = r0 + row;
                    if (i < NN) h_out[(size_t)i * 128 + col] = acc[m][c][g] + bb;
                }
            }
    }
}

extern "C" void kernel_launch(void* const* d_in, const int* in_sizes, int n_in,
                              void* d_out, int out_size, void* d_ws, size_t ws_size,
                              hipStream_t stream) {
    const float* h    = (const float*)d_in[0];
    const float* feat = (const float*)d_in[1];
    const float* ts   = (const float*)d_in[2];
    const float* lu   = (const float*)d_in[3];
    const float* tw   = (const float*)d_in[4];
    const float* tb   = (const float*)d_in[5];
    const float* W1   = (const float*)d_in[6];
    const float* b1   = (const float*)d_in[7];
    const float* W2   = (const float*)d_in[8];
    const float* b2   = (const float*)d_in[9];
    const float* mW1  = (const float*)d_in[10];
    const float* mb1  = (const float*)d_in[11];
    const float* mW2  = (const float*)d_in[12];
    const float* mb2  = (const float*)d_in[13];
    const int*   src  = (const int*)d_in[14];

    __bf16* Wp = (__bf16*)d_ws;                          // 98304 bf16 = 196608 B
    float*  h1 = (float*)((char*)d_ws + 196608);          // 256 MB intermediate
    float*  out = (float*)d_out;

    cvt_weights<<<dim3(384), dim3(256), 0, stream>>>(W1, W2, mW1, mW2, Wp);
    int grid = (NN + TM - 1) / TM;
    tgn_layer<<<dim3(grid), dim3(256), 0, stream>>>(h, feat, ts, lu, tw, tb,
                                                    b1, b2, mb1, mb2, src, Wp, h1);
    tgn_layer<<<dim3(grid), dim3(256), 0, stream>>>(h1, feat, ts, lu, tw, tb,
                                                    b1, b2, mb1, mb2, src, Wp, out);
}

// Round 2
// 644.939 us; speedup vs baseline: 1.0769x; 1.0769x over previous
//
#include <hip/hip_runtime.h>
#include <hip/hip_bf16.h>

#define NN 500000
#define TM 64

typedef __bf16 bf16x8 __attribute__((ext_vector_type(8)));
typedef float  fx4    __attribute__((ext_vector_type(4)));

// ---- prep: Wc = W2@W1 -> bf16 [128][256]; cast mW1,mW2; bc = b2 + W2@b1 ----
__global__ __launch_bounds__(256) void prep(const float* __restrict__ W1,
    const float* __restrict__ W2, const float* __restrict__ mW1,
    const float* __restrict__ mW2, const float* __restrict__ b1,
    const float* __restrict__ b2, __bf16* __restrict__ Wp, float* __restrict__ bc) {
    __shared__ float w2row[128];
    int o = blockIdx.x, k = threadIdx.x;
    if (k < 128) w2row[k] = W2[o * 128 + k];
    __syncthreads();
    float acc = 0.f;
    for (int j = 0; j < 128; ++j) acc += w2row[j] * W1[j * 256 + k];
    int idx = o * 256 + k;
    Wp[idx] = (__bf16)acc;                       // Wc [128][256]
    Wp[32768 + idx] = (__bf16)mW1[idx];          // mW1 [128][256]
    if (idx < 16384) Wp[65536 + idx] = (__bf16)mW2[idx];  // mW2 [128][128]
    if (k == 0) {
        float a = b2[o];
        for (int j = 0; j < 128; ++j) a += w2row[j] * b1[j];
        bc[o] = a;
    }
}

// per-wave GEMM: A in LDS (swizzled, strideB bytes/row, 64 rows) x B^T (global
// bf16 row-major [128][K]) -> acc[4][2] 16x16 tiles; wave covers cols wid*32..+32.
__device__ __forceinline__ void gemm_block(const char* A, int strideB, int K,
                                           const __bf16* B, int lane, int wid,
                                           fx4 acc[4][2]) {
    const int rl = lane & 15, ks = lane >> 4;
    for (int kt = 0; kt < K; kt += 32) {
        const int kb = 2 * kt + 16 * ks;
        bf16x8 a[4], b[2];
#pragma unroll
        for (int m = 0; m < 4; ++m) {
            int row = m * 16 + rl;
            a[m] = *(const bf16x8*)(A + row * strideB + (kb ^ ((row & 7) << 4)));
        }
#pragma unroll
        for (int c = 0; c < 2; ++c) {
            int col = wid * 32 + c * 16 + rl;
            b[c] = *(const bf16x8*)((const char*)B + (size_t)col * 2 * K + kb);
        }
#pragma unroll
        for (int m = 0; m < 4; ++m)
#pragma unroll
            for (int c = 0; c < 2; ++c)
                acc[m][c] = __builtin_amdgcn_mfma_f32_16x16x32_bf16(a[m], b[c], acc[m][c], 0, 0, 0);
    }
}

// L=0: f32 h/feat in, compute te, write fte(bf16) + h1(bf16)
// L=1: bf16 h1/fte in, write f32 out
template<int L>
__global__ __launch_bounds__(256, 5) void tgn_layer(
    const float* __restrict__ hin32, const __bf16* __restrict__ hin16,
    __bf16* __restrict__ fte, const float* __restrict__ feat,
    const float* __restrict__ ts,  const float* __restrict__ lu,
    const float* __restrict__ tw,  const float* __restrict__ tb,
    const int* __restrict__ src,   const __bf16* __restrict__ Wp,
    const float* __restrict__ bc,  const float* __restrict__ mb1,
    const float* __restrict__ mb2, __bf16* __restrict__ hnext,
    float* __restrict__ out32)
{
    __shared__ char C[TM * 512];   // 32 KB, the only LDS buffer (aliased per phase)

    const int tid = threadIdx.x;
    const int r0  = blockIdx.x * TM;
    const int lane = tid & 63, wid = tid >> 6;
    const int rl = lane & 15, ks = lane >> 4;

    // ---- Phase 1: C = [ bf16(h[src]) | fte ] ----
    {
        const int rr = tid >> 4;
        const int cc = (tid & 15) * 8;
#pragma unroll
        for (int rb = 0; rb < 4; ++rb) {
            int r = rr + rb * 16;
            int i = r0 + r; if (i >= NN) i = NN - 1;
            int s = src[i];
            bf16x8 hv, fv;
            if (L == 0) {
                float dt = ts[i] - lu[s];
                const fx4 tw0 = *(const fx4*)(tw + cc), tw1 = *(const fx4*)(tw + cc + 4);
                const fx4 tb0 = *(const fx4*)(tb + cc), tb1 = *(const fx4*)(tb + cc + 4);
                const float i2p = 0.15915494309189535f;
                const fx4* hp = (const fx4*)(hin32 + (size_t)s * 128 + cc);
                const fx4* fp = (const fx4*)(feat + (size_t)i * 128 + cc);
                fx4 h0 = hp[0], h1 = hp[1], f0 = fp[0], f1 = fp[1];
#pragma unroll
                for (int j = 0; j < 4; ++j) {
                    hv[j]     = (__bf16)h0[j];
                    hv[4 + j] = (__bf16)h1[j];
                    float a0 = (dt * tw0[j] + tb0[j]) * i2p;
                    float a1 = (dt * tw1[j] + tb1[j]) * i2p;
                    fv[j]     = (__bf16)(f0[j] + __builtin_amdgcn_cosf(__builtin_amdgcn_fractf(a0)));
                    fv[4 + j] = (__bf16)(f1[j] + __builtin_amdgcn_cosf(__builtin_amdgcn_fractf(a1)));
                }
                *(bf16x8*)((char*)fte + (size_t)i * 256 + 2 * cc) = fv;  // reuse in layer 2
            } else {
                hv = *(const bf16x8*)(hin16 + (size_t)s * 128 + cc);
                fv = *(const bf16x8*)(fte + (size_t)i * 128 + cc);
            }
            int swz = (r & 7) << 4;
            *(bf16x8*)(C + r * 512 + ((2 * cc) ^ swz))       = hv;
            *(bf16x8*)(C + r * 512 + ((256 + 2 * cc) ^ swz)) = fv;
        }
    }
    __syncthreads();

    // ---- Phase 2: hb = relu(C @ Wc^T + bc);  x = [bf16(h_in) | hb] -> C ----
    {
        fx4 acc[4][2] = {};
        gemm_block(C, 512, 256, Wp, lane, wid, acc);
        float bb0 = bc[wid * 32 + rl], bb1 = bc[wid * 32 + 16 + rl];
        __syncthreads();                       // all reads of C done
#pragma unroll
        for (int m = 0; m < 4; ++m)
#pragma unroll
            for (int c = 0; c < 2; ++c) {
                int col = wid * 32 + c * 16 + rl;
                float bb = c ? bb1 : bb0;
#pragma unroll
                for (int g = 0; g < 4; ++g) {
                    int row = m * 16 + ks * 4 + g;
                    float v = fmaxf(acc[m][c][g] + bb, 0.0f);
                    *(__bf16*)(C + row * 512 + ((256 + 2 * col) ^ ((row & 7) << 4))) = (__bf16)v;
                }
            }
        // h-half of x
        const int rr = tid >> 4;
        const int cc = (tid & 15) * 8;
#pragma unroll
        for (int rb = 0; rb < 4; ++rb) {
            int r = rr + rb * 16;
            int i = r0 + r; if (i >= NN) i = NN - 1;
            bf16x8 hv;
            if (L == 0) {
                const fx4* hp = (const fx4*)(hin32 + (size_t)i * 128 + cc);
                fx4 h0 = hp[0], h1 = hp[1];
#pragma unroll
                for (int j = 0; j < 4; ++j) { hv[j] = (__bf16)h0[j]; hv[4 + j] = (__bf16)h1[j]; }
            } else {
                hv = *(const bf16x8*)(hin16 + (size_t)i * 128 + cc);
            }
            *(bf16x8*)(C + r * 512 + ((2 * cc) ^ ((r & 7) << 4))) = hv;
        }
    }
    __syncthreads();

    // ---- Phase 3: m1 = relu(x @ mW1^T + mb1) -> C first half ----
    {
        fx4 acc[4][2] = {};
        gemm_block(C, 512, 256, Wp + 32768, lane, wid, acc);
        float bb0 = mb1[wid * 32 + rl], bb1 = mb1[wid * 32 + 16 + rl];
        __syncthreads();
#pragma unroll
        for (int m = 0; m < 4; ++m)
#pragma unroll
            for (int c = 0; c < 2; ++c) {
                int col = wid * 32 + c * 16 + rl;
                float bb = c ? bb1 : bb0;
#pragma unroll
                for (int g = 0; g < 4; ++g) {
                    int row = m * 16 + ks * 4 + g;
                    float v = fmaxf(acc[m][c][g] + bb, 0.0f);
                    *(__bf16*)(C + row * 512 + ((2 * col) ^ ((row & 7) << 4))) = (__bf16)v;
                }
            }
    }
    __syncthreads();

    // ---- Phase 4: out = m1 @ mW2^T + mb2 (K=128), repack via LDS, store ----
    {
        fx4 acc[4][2] = {};
        gemm_block(C, 512, 128, Wp + 65536, lane, wid, acc);
        float bb0 = mb2[wid * 32 + rl], bb1 = mb2[wid * 32 + 16 + rl];
        __syncthreads();
        if (L == 0) {
#pragma unroll
            for (int m = 0; m < 4; ++m)
#pragma unroll
                for (int c = 0; c < 2; ++c) {
                    int col = wid * 32 + c * 16 + rl;
                    float bb = c ? bb1 : bb0;
#pragma unroll
                    for (int g = 0; g < 4; ++g) {
                        int row = m * 16 + ks * 4 + g;
                        *(__bf16*)(C + row * 256 + 2 * col) = (__bf16)(acc[m][c][g] + bb);
                    }
                }
            __syncthreads();
#pragma unroll
            for (int it = 0; it < 4; ++it) {
                int r = (tid >> 4) + 16 * it;
                int i = r0 + r;
                if (i < NN)
                    *(bf16x8*)((char*)hnext + (size_t)i * 256 + (tid & 15) * 16) =
                        *(const bf16x8*)(C + r * 256 + (tid & 15) * 16);
            }
        } else {
#pragma unroll
            for (int m = 0; m < 4; ++m)
#pragma unroll
                for (int c = 0; c < 2; ++c) {
                    int col = wid * 32 + c * 16 + rl;
                    float bb = c ? bb1 : bb0;
#pragma unroll
                    for (int g = 0; g < 4; ++g) {
                        int row = m * 16 + ks * 4 + g;
                        *(float*)(C + row * 512 + 4 * col) = acc[m][c][g] + bb;
                    }
                }
            __syncthreads();
#pragma unroll
            for (int it = 0; it < 8; ++it) {
                int r = (tid >> 5) + 8 * it;
                int i = r0 + r;
                if (i < NN)
                    *(fx4*)((char*)out32 + (size_t)i * 512 + (tid & 31) * 16) =
                        *(const fx4*)(C + r * 512 + (tid & 31) * 16);
            }
        }
    }
}

extern "C" void kernel_launch(void* const* d_in, const int* in_sizes, int n_in,
                              void* d_out, int out_size, void* d_ws, size_t ws_size,
                              hipStream_t stream) {
    const float* h    = (const float*)d_in[0];
    const float* feat = (const float*)d_in[1];
    const float* ts   = (const float*)d_in[2];
    const float* lu   = (const float*)d_in[3];
    const float* tw   = (const float*)d_in[4];
    const float* tb   = (const float*)d_in[5];
    const float* W1   = (const float*)d_in[6];
    const float* b1   = (const float*)d_in[7];
    const float* W2   = (const float*)d_in[8];
    const float* b2   = (const float*)d_in[9];
    const float* mW1  = (const float*)d_in[10];
    const float* mb1  = (const float*)d_in[11];
    const float* mW2  = (const float*)d_in[12];
    const float* mb2  = (const float*)d_in[13];
    const int*   src  = (const int*)d_in[14];

    char* ws = (char*)d_ws;
    __bf16* Wp  = (__bf16*)ws;                       // 81920 bf16 = 163840 B
    float*  bcb = (float*)(ws + 163840);             // 128 f32
    __bf16* fte = (__bf16*)(ws + 196608);            // 500000*128 bf16 = 128 MB
    __bf16* h1  = (__bf16*)(ws + 196608 + 128000000);// 128 MB
    float*  out = (float*)d_out;

    prep<<<dim3(128), dim3(256), 0, stream>>>(W1, W2, mW1, mW2, b1, b2, Wp, bcb);
    int grid = (NN + TM - 1) / TM;
    tgn_layer<0><<<dim3(grid), dim3(256), 0, stream>>>(h, nullptr, fte, feat, ts, lu,
        tw, tb, src, Wp, bcb, mb1, mb2, h1, nullptr);
    tgn_layer<1><<<dim3(grid), dim3(256), 0, stream>>>(nullptr, h1, fte, feat, ts, lu,
        tw, tb, src, Wp, bcb, mb1, mb2, nullptr, out);
}